// Round 6
// baseline (2611.119 us; speedup 1.0000x reference)
//
#include <hip/hip_runtime.h>
#include <math.h>

#define TT   16
#define BATCH 8
#define HH   64
#define WW   64
#define HWSZ 4096
#define HID  32
#define NBLK 512
#define CT_STRIDE 68

typedef __bf16 bf16x8 __attribute__((ext_vector_type(8)));
typedef float  f32x4  __attribute__((ext_vector_type(4)));
typedef unsigned short u16;
typedef unsigned int   u32;

__device__ __forceinline__ u16 f2bf(float f) {
    union { float f; u32 u; } v; v.f = f;
    u32 r = v.u + 0x7FFF + ((v.u >> 16) & 1);   // RNE
    return (u16)(r >> 16);
}

// ---- prep: x [T,B,16,H,W] fp32 -> xbf [T*B*4096 pixels][16 cin] bf16 ----
__global__ __launch_bounds__(256)
void prep_x(const float* __restrict__ x, u16* __restrict__ xbf) {
    const int p = blockIdx.x * 256 + threadIdx.x;
    const int tb = p >> 12, pix = p & 4095;
    const float* src = x + ((size_t)tb * 16) * HWSZ + pix;
    u16 o[16];
#pragma unroll
    for (int c = 0; c < 16; ++c) o[c] = f2bf(src[(size_t)c * HWSZ]);
    uint4* dst = (uint4*)(xbf + (size_t)p * 16);
    dst[0] = *(uint4*)&o[0];
    dst[1] = *(uint4*)&o[8];
}

// ---- prep: W [128,CIN_L,3,3] fp32 -> MFMA B-frag order [tap][kc][nt][lane][8] bf16
__global__ __launch_bounds__(256)
void prep_w(const float* __restrict__ W, u16* __restrict__ wf, int cinl) {
    const int idx = blockIdx.x * 256 + threadIdx.x;   // [0, 9216)
    const int lane = idx & 63, nt = (idx >> 6) & 7, kc = (idx >> 9) & 1, tap = idx >> 10;
    const int cho = nt * 16 + (lane & 15);
    const int cb  = kc * 32 + ((lane >> 4) * 8);
    u16 o[8];
#pragma unroll
    for (int j = 0; j < 8; ++j) {
        const int cin = cb + j;
        o[j] = (cin < cinl) ? f2bf(W[((size_t)cho * cinl + cin) * 9 + tap]) : (u16)0;
    }
    ((uint4*)wf)[idx] = *(uint4*)&o[0];
}

// ---- device-scope grid barrier (counter + epoch, replay-safe via memset) ----
__device__ __forceinline__ void gbar(u32* bar, u32 ep) {
    __threadfence();                 // release prior writes device-wide
    __syncthreads();
    if (threadIdx.x == 0) {
        u32 old = __hip_atomic_fetch_add(&bar[0], 1u, __ATOMIC_ACQ_REL,
                                         __HIP_MEMORY_SCOPE_AGENT);
        if (old == NBLK - 1) {
            __hip_atomic_store(&bar[0], 0u, __ATOMIC_RELAXED,
                               __HIP_MEMORY_SCOPE_AGENT);
            __hip_atomic_fetch_add(&bar[1], 1u, __ATOMIC_RELEASE,
                                   __HIP_MEMORY_SCOPE_AGENT);
        } else {
            while (__hip_atomic_load(&bar[1], __ATOMIC_ACQUIRE,
                                     __HIP_MEMORY_SCOPE_AGENT) < ep)
                __builtin_amdgcn_s_sleep(8);
        }
    }
    __syncthreads();
}

// ---- persistent fused ConvLSTM: all 17 (t,layer) steps in one kernel ----
// Block roles fixed for the whole run: blockIdx.x<256 -> layer0, else layer1;
// blk&255 -> b = blk>>5, y0 = (blk&31)*2. Cell state c lives in registers.
__global__ __launch_bounds__(256, 3)
void persistent_lstm(
    const u16* __restrict__ xbf,
    const uint4* __restrict__ wf0, const uint4* __restrict__ wf1,
    const float* __restrict__ bias0, const float* __restrict__ bias1,
    u16* __restrict__ h0a, u16* __restrict__ h0b,      // layer0 h ping-pong (bf16 pixel-major)
    u16* __restrict__ h1a, u16* __restrict__ h1b,      // layer1 h ping-pong
    float* __restrict__ hseq0, float* __restrict__ hseq1,
    float* __restrict__ h0T, float* __restrict__ c0T,
    float* __restrict__ h1T, float* __restrict__ c1T,
    u32* __restrict__ bar)
{
    __shared__ uint4 lds4[2112];              // 33,792 B: A-tile, then h/c transpose tile

    const int tid  = threadIdx.x;
    const int half = (blockIdx.x >= 256);     // 0 = layer0, 1 = layer1
    const int blk  = blockIdx.x & 255;
    const int y0   = (blk & 31) * 2;
    const int b    = blk >> 5;

    const int   xch  = half ? 32 : 16;
    const uint4* wf  = half ? wf1 : wf0;
    const float* bias= half ? bias1 : bias0;
    u16* hA          = half ? h1a : h0a;      // this layer's ping-pong
    u16* hB          = half ? h1b : h0b;
    float* hseq      = half ? hseq1 : hseq0;
    float* hTp       = half ? h1T : h0T;
    float* cTp       = half ? c1T : c0T;

    const int lane = tid & 63, w = tid >> 6;
    const int l15 = lane & 15, lhi = lane >> 4;
    const int khalf = w & 1, wrow = w >> 1;

    float bv[4];
#pragma unroll
    for (int n = 0; n < 4; ++n) bv[n] = bias[n * 32 + khalf * 16 + l15];

    float creg[4][4];                          // running cell state (this thread's frags)
#pragma unroll
    for (int m = 0; m < 4; ++m)
#pragma unroll
        for (int rr = 0; rr < 4; ++rr) creg[m][rr] = 0.f;

    // flush-phase indexing (coalesced channel-major I/O)
    const int fr  = tid >> 2;                  // 0..63: row = fyy*32 + fc
    const int fyy = fr >> 5, fc = fr & 31;
    const size_t gflat = ((size_t)(b * HID + fc) * HH + (y0 + fyy)) * WW;

    const int c   = khalf * 16 + l15;          // this thread's hid channel
    const int row = wrow * 32 + c;             // transpose-tile row
    const size_t hb_base = (size_t)b * HWSZ + (size_t)(y0 + wrow) * WW;
    const size_t xstep = (size_t)BATCH * HWSZ * 16;
    const size_t hstep = (size_t)BATCH * HID * HWSZ;

    u32 ep = 0;
    for (int d = 0; d <= TT; ++d) {
        if (d) { ++ep; gbar(bar, ep); }

        const int  t      = half ? d - 1 : d;
        const bool active = half ? (d >= 1) : (d < TT);
        if (!active) continue;
        const bool first  = (t == 0);
        const bool finals = (t == TT - 1);

        const u16* srcX = half ? ((t & 1) ? h0b : h0a) : xbf + (size_t)t * xstep;
        const u16* srcH = ((t - 1) & 1) ? hB : hA;
        u16*       hbfo = (t & 1) ? hB : hA;
        float*     hout = hseq + (size_t)t * hstep;

        // ---- stage 4 rows x 66 px x 64 cin (16B chunks), XOR-swizzled ----
        for (int q = tid; q < 2112; q += 256) {
            const int c8 = q & 7;
            const int pr = q >> 3;
            const int px = pr % 66;
            const int r  = pr / 66;
            const int gy = y0 - 1 + r;
            const int gx = px - 1;
            uint4 v = {0u, 0u, 0u, 0u};
            if (gy >= 0 && gy < HH && gx >= 0 && gx < WW) {
                const int pix = b * HWSZ + gy * WW + gx;
                const int cin8 = c8 * 8;
                if (cin8 < xch) {
                    v = *(const uint4*)(srcX + (size_t)pix * xch + cin8);
                } else if (cin8 < xch + 32) {
                    if (!first) v = *(const uint4*)(srcH + (size_t)pix * 32 + (cin8 - xch));
                }
            }
            lds4[(pr * 8 + c8) ^ (px & 7)] = v;
        }
        __syncthreads();

        // ---- MFMA: 9 taps x 2 k-cells x (4m x 4n) ----
        f32x4 acc[4][4];
#pragma unroll
        for (int m = 0; m < 4; ++m)
#pragma unroll
            for (int n = 0; n < 4; ++n)
                acc[m][n] = (f32x4){bv[n], bv[n], bv[n], bv[n]};

        const int p0 = l15 + 1;
#pragma unroll
        for (int tap = 0; tap < 9; ++tap) {
            const int sr = wrow + tap / 3;
            const int dx = tap % 3 - 1;
#pragma unroll
            for (int kc = 0; kc < 2; ++kc) {
                const int kcell = kc * 4 + lhi;
                bf16x8 a[4];
#pragma unroll
                for (int m = 0; m < 4; ++m) {
                    const int pxt = p0 + m * 16 + dx;
                    a[m] = __builtin_bit_cast(bf16x8,
                            lds4[(((sr * 66 + pxt) * 8) + kcell) ^ (pxt & 7)]);
                }
#pragma unroll
                for (int n = 0; n < 4; ++n) {
                    const bf16x8 bw = __builtin_bit_cast(bf16x8,
                            wf[((tap * 2 + kc) * 8 + (khalf + 2 * n)) * 64 + lane]);
#pragma unroll
                    for (int m = 0; m < 4; ++m)
                        acc[m][n] = __builtin_amdgcn_mfma_f32_16x16x32_bf16(
                                        a[m], bw, acc[m][n], 0, 0, 0);
                }
            }
        }
        __syncthreads();                        // A-tile free -> reuse as htile

        // ---- LSTM pointwise epilogue: c stays in registers ----
        float* htile = (float*)lds4;
#pragma unroll
        for (int m = 0; m < 4; ++m) {
#pragma unroll
            for (int rr = 0; rr < 4; ++rr) {
                const int p = m * 16 + lhi * 4 + rr;
                const float cp = creg[m][rr];
                const float iv = acc[m][0][rr], fv = acc[m][1][rr];
                const float ov = acc[m][2][rr], gv = acc[m][3][rr];
                const float ig = __builtin_amdgcn_rcpf(1.f + __expf(-iv));
                const float fg = __builtin_amdgcn_rcpf(1.f + __expf(-fv));
                const float og = __builtin_amdgcn_rcpf(1.f + __expf(-ov));
                const float gg = 1.f - 2.f * __builtin_amdgcn_rcpf(1.f + __expf(2.f * gv));
                const float cn = fg * cp + ig * gg;
                const float hn = og * (1.f - 2.f * __builtin_amdgcn_rcpf(1.f + __expf(2.f * cn)));
                creg[m][rr] = cn;
                htile[row * CT_STRIDE + p] = hn;
                hbfo[(hb_base + p) * 32 + c] = f2bf(hn);
            }
        }
        __syncthreads();

        // ---- coalesced flush: htile -> hseq[t] (+hT at final step) ----
#pragma unroll
        for (int j = 0; j < 4; ++j) {
            const int q = j * 4 + (tid & 3);
            const uint4 hv = *(const uint4*)(htile + fr * CT_STRIDE + q * 4);
            *(uint4*)(hout + gflat + q * 4) = hv;
            if (finals) *(uint4*)(hTp + gflat + q * 4) = hv;
        }

        if (finals) {
            __syncthreads();
            float* ctile = (float*)lds4;
#pragma unroll
            for (int m = 0; m < 4; ++m)
#pragma unroll
                for (int rr = 0; rr < 4; ++rr)
                    ctile[row * CT_STRIDE + (m * 16 + lhi * 4 + rr)] = creg[m][rr];
            __syncthreads();
#pragma unroll
            for (int j = 0; j < 4; ++j) {
                const int q = j * 4 + (tid & 3);
                *(uint4*)(cTp + gflat + q * 4) =
                    *(const uint4*)(ctile + fr * CT_STRIDE + q * 4);
            }
        }
    }
}

extern "C" void kernel_launch(void* const* d_in, const int* in_sizes, int n_in,
                              void* d_out, int out_size, void* d_ws, size_t ws_size,
                              hipStream_t stream) {
    const float* x  = (const float*)d_in[0];
    const float* W0 = (const float*)d_in[1];
    const float* b0 = (const float*)d_in[2];
    const float* W1 = (const float*)d_in[3];
    const float* b1 = (const float*)d_in[4];
    float* out = (float*)d_out;

    float* hseq0 = out;
    float* hseq1 = out + 16777216;
    float* h0T   = out + 33554432;
    float* c0T   = out + 34603008;
    float* h1T   = out + 35651584;
    float* c1T   = out + 36700160;

    // ws layout (bytes): xbf 16,777,216 | wf0 147,456 | wf1 147,456 |
    //                    h0 ping-pong 2x2,097,152 | h1 ping-pong 2x2,097,152
    // barrier: 64B-aligned at the tail of ws.
    char* ws = (char*)d_ws;
    u16*  xbf = (u16*)ws;
    u16*  wf0 = (u16*)(ws + 16777216);
    u16*  wf1 = (u16*)(ws + 16777216 + 147456);
    u16*  h0a = (u16*)(ws + 17072128);
    u16*  h0b = (u16*)(ws + 17072128 + 2097152);
    u16*  h1a = (u16*)(ws + 21266432);
    u16*  h1b = (u16*)(ws + 21266432 + 2097152);
    u32*  bar = (u32*)(ws + ((ws_size - 64) & ~(size_t)63));

    hipMemsetAsync(bar, 0, 8, stream);
    prep_x<<<2048, 256, 0, stream>>>(x, xbf);
    prep_w<<<36, 256, 0, stream>>>(W0, wf0, 48);
    prep_w<<<36, 256, 0, stream>>>(W1, wf1, 64);

    persistent_lstm<<<NBLK, 256, 0, stream>>>(
        xbf, (const uint4*)wf0, (const uint4*)wf1, b0, b1,
        h0a, h0b, h1a, h1b,
        hseq0, hseq1, h0T, c0T, h1T, c1T, bar);
}

// Round 8
// 1066.005 us; speedup vs baseline: 2.4494x; 2.4494x over previous
//
#include <hip/hip_runtime.h>
#include <math.h>

#define TT   16
#define BATCH 8
#define HH   64
#define WW   64
#define HWSZ 4096
#define HID  32
#define NBLK 512
#define CT_STRIDE 68

typedef __bf16 bf16x8 __attribute__((ext_vector_type(8)));
typedef float  f32x4  __attribute__((ext_vector_type(4)));
typedef unsigned short u16;
typedef unsigned int   u32;
typedef unsigned long long u64;
typedef u32 u32x4 __attribute__((ext_vector_type(4)));   // clang vector: ok for nontemporal builtins

__device__ __forceinline__ u16 f2bf(float f) {
    union { float f; u32 u; } v; v.f = f;
    u32 r = v.u + 0x7FFF + ((v.u >> 16) & 1);   // RNE
    return (u16)(r >> 16);
}

// RELAXED agent-scope (sc1) ops: routed to the device coherence point, never
// cached in XCD L2 -> cross-XCD safe with NO buffer_inv / buffer_wbl2 storms
// (v6's ACQUIRE spin invalidated all 8 L2s continuously -> 8x regression).
__device__ __forceinline__ u64 ald(const u16* p) {
    return __hip_atomic_load((const u64*)p, __ATOMIC_RELAXED,
                             __HIP_MEMORY_SCOPE_AGENT);
}
__device__ __forceinline__ void ast(u16* p, u64 v) {
    __hip_atomic_store((u64*)p, v, __ATOMIC_RELAXED, __HIP_MEMORY_SCOPE_AGENT);
}

// ---- prep: x [T,B,16,H,W] fp32 -> xbf [T*B*4096 pixels][16 cin] bf16 ----
__global__ __launch_bounds__(256)
void prep_x(const float* __restrict__ x, u16* __restrict__ xbf) {
    const int p = blockIdx.x * 256 + threadIdx.x;
    const int tb = p >> 12, pix = p & 4095;
    const float* src = x + ((size_t)tb * 16) * HWSZ + pix;
    u16 o[16];
#pragma unroll
    for (int c = 0; c < 16; ++c) o[c] = f2bf(src[(size_t)c * HWSZ]);
    uint4* dst = (uint4*)(xbf + (size_t)p * 16);
    dst[0] = *(uint4*)&o[0];
    dst[1] = *(uint4*)&o[8];
}

// ---- prep: W [128,CIN_L,3,3] fp32 -> MFMA B-frag order [tap][kc][nt][lane][8] bf16
__global__ __launch_bounds__(256)
void prep_w(const float* __restrict__ W, u16* __restrict__ wf, int cinl) {
    const int idx = blockIdx.x * 256 + threadIdx.x;   // [0, 9216)
    const int lane = idx & 63, nt = (idx >> 6) & 7, kc = (idx >> 9) & 1, tap = idx >> 10;
    const int cho = nt * 16 + (lane & 15);
    const int cb  = kc * 32 + ((lane >> 4) * 8);
    u16 o[8];
#pragma unroll
    for (int j = 0; j < 8; ++j) {
        const int cin = cb + j;
        o[j] = (cin < cinl) ? f2bf(W[((size_t)cho * cinl + cin) * 9 + tap]) : (u16)0;
    }
    ((uint4*)wf)[idx] = *(uint4*)&o[0];
}

// ---- grid barrier: monotonic arrival counter + epoch, ALL RELAXED ----
// __syncthreads() before arrival drains vmcnt(0) (compiler-emitted), so all
// sc1 data stores are at the coherence point before the arrival add lands.
__device__ __forceinline__ void gbar(u32* bar, u32 ep) {
    __syncthreads();
    if (threadIdx.x == 0) {
        const u32 old = __hip_atomic_fetch_add(&bar[0], 1u, __ATOMIC_RELAXED,
                                               __HIP_MEMORY_SCOPE_AGENT);
        if (old == ep * NBLK - 1u) {
            __hip_atomic_fetch_add(&bar[1], 1u, __ATOMIC_RELAXED,
                                   __HIP_MEMORY_SCOPE_AGENT);
        } else {
            while (__hip_atomic_load(&bar[1], __ATOMIC_RELAXED,
                                     __HIP_MEMORY_SCOPE_AGENT) < ep)
                __builtin_amdgcn_s_sleep(2);
        }
    }
    __syncthreads();
}

// ---- persistent fused ConvLSTM: all 17 (t,layer) steps in one kernel ----
// blockIdx.x<256 -> layer0, else layer1; blk&255 -> b = blk>>5, y0 = (blk&31)*2.
// Cell state c lives in registers for the entire sequence.
__global__ __launch_bounds__(256, 3)
void persistent_lstm(
    const u16* __restrict__ xbf,
    const uint4* __restrict__ wf0, const uint4* __restrict__ wf1,
    const float* __restrict__ bias0, const float* __restrict__ bias1,
    u16* __restrict__ h0a, u16* __restrict__ h0b,
    u16* __restrict__ h1a, u16* __restrict__ h1b,
    float* __restrict__ hseq0, float* __restrict__ hseq1,
    float* __restrict__ h0T, float* __restrict__ c0T,
    float* __restrict__ h1T, float* __restrict__ c1T,
    u32* __restrict__ bar)
{
    __shared__ uint4 lds4[2112];              // 33,792 B: A-tile / h-tile / c-tile

    const int tid  = threadIdx.x;
    const int half = (blockIdx.x >= 256);     // 0 = layer0, 1 = layer1
    const int blk  = blockIdx.x & 255;
    const int y0   = (blk & 31) * 2;
    const int b    = blk >> 5;

    const uint4* wf   = half ? wf1 : wf0;
    const float* bias = half ? bias1 : bias0;
    u16* hA           = half ? h1a : h0a;
    u16* hB           = half ? h1b : h0b;
    float* hseq       = half ? hseq1 : hseq0;
    float* hTp        = half ? h1T : h0T;
    float* cTp        = half ? c1T : c0T;

    const int lane = tid & 63, w = tid >> 6;
    const int l15 = lane & 15, lhi = lane >> 4;
    const int khalf = w & 1, wrow = w >> 1;

    float bv[4];
#pragma unroll
    for (int n = 0; n < 4; ++n) bv[n] = bias[n * 32 + khalf * 16 + l15];

    float creg[4][4];
#pragma unroll
    for (int m = 0; m < 4; ++m)
#pragma unroll
        for (int rr = 0; rr < 4; ++rr) creg[m][rr] = 0.f;

    const int fr  = tid >> 2;                  // flush row 0..63 (fyy*32+fc)
    const int fyy = fr >> 5, fc = fr & 31;
    const size_t gflat = ((size_t)(b * HID + fc) * HH + (y0 + fyy)) * WW;

    const int c   = khalf * 16 + l15;
    const int row = wrow * 32 + c;
    const size_t xstep = (size_t)BATCH * HWSZ * 16;
    const size_t hstep = (size_t)BATCH * HID * HWSZ;

    for (int d = 0; d <= TT; ++d) {
        if (d) gbar(bar, (u32)d);

        const int  t      = half ? d - 1 : d;
        const bool active = half ? (d >= 1) : (d < TT);
        if (!active) continue;
        const bool first  = (t == 0);
        const bool finals = (t == TT - 1);

        const u16* srcX = half ? ((t & 1) ? h0b : h0a) : xbf + (size_t)t * xstep;
        const u16* srcH = ((t - 1) & 1) ? hB : hA;
        u16*       hbfo = (t & 1) ? hB : hA;
        float*     hout = hseq + (size_t)t * hstep;

        // ---- stage 4 rows x 66 px x 64 cin, XOR-swizzled; h via sc1 loads ----
        for (int q = tid; q < 2112; q += 256) {
            const int c8 = q & 7;
            const int pr = q >> 3;
            const int px = pr % 66;
            const int r  = pr / 66;
            const int gy = y0 - 1 + r;
            const int gx = px - 1;
            uint4 v = {0u, 0u, 0u, 0u};
            if (gy >= 0 && gy < HH && gx >= 0 && gx < WW) {
                const int pix = b * HWSZ + gy * WW + gx;
                const int cin8 = c8 * 8;
                if (!half) {
                    if (cin8 < 16) {
                        v = *(const uint4*)(srcX + (size_t)pix * 16 + cin8);
                    } else if (!first) {
                        const u16* s = srcH + (size_t)pix * 32 + (cin8 - 16);
                        ((u64*)&v)[0] = ald(s);
                        ((u64*)&v)[1] = ald(s + 4);
                    }
                } else {
                    if (cin8 < 32) {
                        const u16* s = srcX + (size_t)pix * 32 + cin8;
                        ((u64*)&v)[0] = ald(s);
                        ((u64*)&v)[1] = ald(s + 4);
                    } else if (!first) {
                        const u16* s = srcH + (size_t)pix * 32 + (cin8 - 32);
                        ((u64*)&v)[0] = ald(s);
                        ((u64*)&v)[1] = ald(s + 4);
                    }
                }
            }
            lds4[(pr * 8 + c8) ^ (px & 7)] = v;
        }
        __syncthreads();

        // ---- MFMA: 9 taps x 2 k-cells x (4m x 4n) ----
        f32x4 acc[4][4];
#pragma unroll
        for (int m = 0; m < 4; ++m)
#pragma unroll
            for (int n = 0; n < 4; ++n)
                acc[m][n] = (f32x4){bv[n], bv[n], bv[n], bv[n]};

        const int p0 = l15 + 1;
#pragma unroll
        for (int tap = 0; tap < 9; ++tap) {
            const int sr = wrow + tap / 3;
            const int dx = tap % 3 - 1;
#pragma unroll
            for (int kc = 0; kc < 2; ++kc) {
                const int kcell = kc * 4 + lhi;
                bf16x8 a[4];
#pragma unroll
                for (int m = 0; m < 4; ++m) {
                    const int pxt = p0 + m * 16 + dx;
                    a[m] = __builtin_bit_cast(bf16x8,
                            lds4[(((sr * 66 + pxt) * 8) + kcell) ^ (pxt & 7)]);
                }
#pragma unroll
                for (int n = 0; n < 4; ++n) {
                    const bf16x8 bw = __builtin_bit_cast(bf16x8,
                            wf[((tap * 2 + kc) * 8 + (khalf + 2 * n)) * 64 + lane]);
#pragma unroll
                    for (int m = 0; m < 4; ++m)
                        acc[m][n] = __builtin_amdgcn_mfma_f32_16x16x32_bf16(
                                        a[m], bw, acc[m][n], 0, 0, 0);
                }
            }
        }
        __syncthreads();                        // A-tile free -> reuse as htile

        // ---- LSTM pointwise epilogue: c stays in registers, h -> LDS ----
        float* htile = (float*)lds4;
#pragma unroll
        for (int m = 0; m < 4; ++m) {
#pragma unroll
            for (int rr = 0; rr < 4; ++rr) {
                const int p = m * 16 + lhi * 4 + rr;
                const float cp = creg[m][rr];
                const float iv = acc[m][0][rr], fv = acc[m][1][rr];
                const float ov = acc[m][2][rr], gv = acc[m][3][rr];
                const float ig = __builtin_amdgcn_rcpf(1.f + __expf(-iv));
                const float fg = __builtin_amdgcn_rcpf(1.f + __expf(-fv));
                const float og = __builtin_amdgcn_rcpf(1.f + __expf(-ov));
                const float gg = 1.f - 2.f * __builtin_amdgcn_rcpf(1.f + __expf(2.f * gv));
                const float cn = fg * cp + ig * gg;
                const float hn = og * (1.f - 2.f * __builtin_amdgcn_rcpf(1.f + __expf(2.f * cn)));
                creg[m][rr] = cn;
                htile[row * CT_STRIDE + p] = hn;
            }
        }
        __syncthreads();

        // ---- flush 1: htile -> hseq[t] fp32 (streaming nt stores, +hT at end) ----
#pragma unroll
        for (int j = 0; j < 4; ++j) {
            const int q = j * 4 + (tid & 3);
            const u32x4 hv = *(const u32x4*)(htile + fr * CT_STRIDE + q * 4);
            __builtin_nontemporal_store(hv, (u32x4*)(hout + gflat + q * 4));
            if (finals)
                __builtin_nontemporal_store(hv, (u32x4*)(hTp + gflat + q * 4));
        }

        // ---- flush 2: htile -> hbf ping-pong, packed u64 sc1 stores ----
#pragma unroll
        for (int j = 0; j < 4; ++j) {
            const int idx = j * 256 + tid;       // 0..1023
            const int c4  = idx & 7;             // 4-channel group
            const int pxx = (idx >> 3) & 63;
            const int yy  = idx >> 9;
            u16 pk[4];
#pragma unroll
            for (int k = 0; k < 4; ++k)
                pk[k] = f2bf(htile[(yy * 32 + c4 * 4 + k) * CT_STRIDE + pxx]);
            const int pix = b * HWSZ + (y0 + yy) * WW + pxx;
            ast(hbfo + (size_t)pix * 32 + c4 * 4, *(u64*)pk);
        }

        // ---- final step: dump register c -> cT (coalesced via LDS) ----
        if (finals) {
            __syncthreads();
            float* ctile = (float*)lds4;
#pragma unroll
            for (int m = 0; m < 4; ++m)
#pragma unroll
                for (int rr = 0; rr < 4; ++rr)
                    ctile[row * CT_STRIDE + (m * 16 + lhi * 4 + rr)] = creg[m][rr];
            __syncthreads();
#pragma unroll
            for (int j = 0; j < 4; ++j) {
                const int q = j * 4 + (tid & 3);
                __builtin_nontemporal_store(
                    *(const u32x4*)(ctile + fr * CT_STRIDE + q * 4),
                    (u32x4*)(cTp + gflat + q * 4));
            }
        }
    }
}

extern "C" void kernel_launch(void* const* d_in, const int* in_sizes, int n_in,
                              void* d_out, int out_size, void* d_ws, size_t ws_size,
                              hipStream_t stream) {
    const float* x  = (const float*)d_in[0];
    const float* W0 = (const float*)d_in[1];
    const float* b0 = (const float*)d_in[2];
    const float* W1 = (const float*)d_in[3];
    const float* b1 = (const float*)d_in[4];
    float* out = (float*)d_out;

    float* hseq0 = out;
    float* hseq1 = out + 16777216;
    float* h0T   = out + 33554432;
    float* c0T   = out + 34603008;
    float* h1T   = out + 35651584;
    float* c1T   = out + 36700160;

    // ws: xbf 16,777,216 | wf0 147,456 | wf1 147,456 | h0 2x2,097,152 |
    //     h1 2x2,097,152 | barrier (64B-aligned tail)
    char* ws = (char*)d_ws;
    u16*  xbf = (u16*)ws;
    u16*  wf0 = (u16*)(ws + 16777216);
    u16*  wf1 = (u16*)(ws + 16777216 + 147456);
    u16*  h0a = (u16*)(ws + 17072128);
    u16*  h0b = (u16*)(ws + 17072128 + 2097152);
    u16*  h1a = (u16*)(ws + 21266432);
    u16*  h1b = (u16*)(ws + 21266432 + 2097152);
    u32*  bar = (u32*)(ws + ((ws_size - 64) & ~(size_t)63));

    (void)hipMemsetAsync(bar, 0, 8, stream);
    prep_x<<<2048, 256, 0, stream>>>(x, xbf);
    prep_w<<<36, 256, 0, stream>>>(W0, wf0, 48);
    prep_w<<<36, 256, 0, stream>>>(W1, wf1, 64);

    persistent_lstm<<<NBLK, 256, 0, stream>>>(
        xbf, (const uint4*)wf0, (const uint4*)wf1, b0, b1,
        h0a, h0b, h1a, h1b,
        hseq0, hseq1, h0T, c0T, h1T, c1T, bar);
}

// Round 9
// 300.846 us; speedup vs baseline: 8.6793x; 3.5434x over previous
//
#include <hip/hip_runtime.h>
#include <math.h>

#define TT   16
#define BATCH 8
#define HH   64
#define WW   64
#define HWSZ 4096
#define HID  32
#define CT_STRIDE 68

typedef __bf16 bf16x8 __attribute__((ext_vector_type(8)));
typedef float  f32x4  __attribute__((ext_vector_type(4)));
typedef unsigned short u16;
typedef unsigned int   u32;
typedef unsigned long long u64;
typedef u32 u32x4 __attribute__((ext_vector_type(4)));   // clang vector for nontemporal stores

__device__ __forceinline__ u16 f2bf(float f) {
    union { float f; u32 u; } v; v.f = f;
    u32 r = v.u + 0x7FFF + ((v.u >> 16) & 1);   // RNE
    return (u16)(r >> 16);
}

// ---- prep: x [T,B,16,H,W] fp32 -> xbf [T*B*4096 pixels][16 cin] bf16 ----
__global__ __launch_bounds__(256)
void prep_x(const float* __restrict__ x, u16* __restrict__ xbf) {
    const int p = blockIdx.x * 256 + threadIdx.x;
    const int tb = p >> 12, pix = p & 4095;
    const float* src = x + ((size_t)tb * 16) * HWSZ + pix;
    u16 o[16];
#pragma unroll
    for (int c = 0; c < 16; ++c) o[c] = f2bf(src[(size_t)c * HWSZ]);
    uint4* dst = (uint4*)(xbf + (size_t)p * 16);
    dst[0] = *(uint4*)&o[0];
    dst[1] = *(uint4*)&o[8];
}

// ---- prep: W [128,CIN_L,3,3] fp32 -> MFMA B-frag order [tap][kc][nt][lane][8] bf16
__global__ __launch_bounds__(256)
void prep_w(const float* __restrict__ W, u16* __restrict__ wf, int cinl) {
    const int idx = blockIdx.x * 256 + threadIdx.x;   // [0, 9216)
    const int lane = idx & 63, nt = (idx >> 6) & 7, kc = (idx >> 9) & 1, tap = idx >> 10;
    const int cho = nt * 16 + (lane & 15);
    const int cb  = kc * 32 + ((lane >> 4) * 8);
    u16 o[8];
#pragma unroll
    for (int j = 0; j < 8; ++j) {
        const int cin = cb + j;
        o[j] = (cin < cinl) ? f2bf(W[((size_t)cho * cinl + cin) * 9 + tap]) : (u16)0;
    }
    ((uint4*)wf)[idx] = *(uint4*)&o[0];
}

// ---- fused ConvLSTM step v8: v5 + 3-deep register pipeline in the K-loop ----
// Per layer-half: 256 blocks; blk -> b = blk>>5, y0 = (blk&31)*2 (2 output rows).
// Block = 4 waves: wave w -> row (w>>1), khalf (w&1). Wave tile M=64 px x N=64 ch.
// K-loop = 18 groups (9 taps x 2 k-cells), 16 MFMAs each; A (LDS) and B (L2
// weights) triple-buffered in registers so ~2 groups of loads stay in flight
// (v5 compiled to VGPR=48 -> no prefetch -> exposed L2 latency per group).
__device__ __forceinline__ void conv_step(
    const u16* __restrict__ srcX, int xch,          // pixel-major bf16 [B*4096][xch]
    const u16* __restrict__ srcH,                   // pixel-major bf16 [B*4096][32]
    const uint4* __restrict__ wf,                   // [9][2][8][64] x 16B
    const float* __restrict__ bias,                 // [128]
    float* __restrict__ cbuf,                       // [B,32,H,W] running c (in/out)
    float* __restrict__ hout, float* __restrict__ hT,
    u16* __restrict__ hbfo,
    int t0, int blk, uint4* lds4, float* ctile)
{
    const int tid = threadIdx.x;
    const int y0 = (blk & 31) * 2;
    const int b  = blk >> 5;

    // ---- stage 4 rows x 66 px x 64 cin (16B chunks), XOR-swizzled ----
    for (int q = tid; q < 2112; q += 256) {
        const int c8 = q & 7;
        const int pr = q >> 3;          // 0..263
        const int px = pr % 66;
        const int r  = pr / 66;         // 0..3  (gy = y0-1+r)
        const int gy = y0 - 1 + r;
        const int gx = px - 1;
        uint4 v = {0u, 0u, 0u, 0u};
        if (gy >= 0 && gy < HH && gx >= 0 && gx < WW) {
            const int pix = b * HWSZ + gy * WW + gx;
            const int cin8 = c8 * 8;
            if (cin8 < xch) {
                v = *(const uint4*)(srcX + (size_t)pix * xch + cin8);
            } else if (cin8 < xch + 32) {
                if (!t0) v = *(const uint4*)(srcH + (size_t)pix * 32 + (cin8 - xch));
            }
        }
        lds4[(pr * 8 + c8) ^ (px & 7)] = v;
    }

    // ---- coalesced c-tile load: cbuf channel-major -> ctile[(yy*32+c)][p] ----
    const int fr  = tid >> 2;          // 0..63
    const int fyy = fr >> 5, fc = fr & 31;
    const size_t gflat = ((size_t)(b * HID + fc) * HH + (y0 + fyy)) * WW;
    if (!t0) {
#pragma unroll
        for (int j = 0; j < 4; ++j) {
            const int q = j * 4 + (tid & 3);   // uint4 idx 0..15 within row
            *(uint4*)(ctile + fr * CT_STRIDE + q * 4) =
                *(const uint4*)(cbuf + gflat + q * 4);
        }
    }
    __syncthreads();

    const int lane  = tid & 63;
    const int w     = tid >> 6;
    const int l15   = lane & 15, lhi = lane >> 4;
    const int khalf = w & 1;
    const int wrow  = w >> 1;           // which of the 2 output rows

    float bv[4];
#pragma unroll
    for (int n = 0; n < 4; ++n) bv[n] = bias[n * 32 + khalf * 16 + l15];
    f32x4 acc[4][4];
#pragma unroll
    for (int m = 0; m < 4; ++m)
#pragma unroll
        for (int n = 0; n < 4; ++n)
            acc[m][n] = (f32x4){bv[n], bv[n], bv[n], bv[n]};

    const int p0 = l15 + 1;   // tile px for dx=0, m=0

    // group g = tap*2 + kc, g in [0,18)
    auto LOADA = [&](bf16x8* dst, int g) {
        const int tap = g >> 1, kc = g & 1;
        const int sr = wrow + tap / 3;
        const int dx = tap % 3 - 1;
        const int kcell = kc * 4 + lhi;
#pragma unroll
        for (int m = 0; m < 4; ++m) {
            const int pxt = p0 + m * 16 + dx;
            dst[m] = __builtin_bit_cast(bf16x8,
                     lds4[(((sr * 66 + pxt) * 8) + kcell) ^ (pxt & 7)]);
        }
    };
    auto LOADB = [&](bf16x8* dst, int g) {
#pragma unroll
        for (int n = 0; n < 4; ++n)
            dst[n] = __builtin_bit_cast(bf16x8,
                     wf[((size_t)g * 8 + (khalf + 2 * n)) * 64 + lane]);
    };
    auto MFMAG = [&](const bf16x8* a, const bf16x8* bw) {
#pragma unroll
        for (int n = 0; n < 4; ++n)
#pragma unroll
            for (int m = 0; m < 4; ++m)
                acc[m][n] = __builtin_amdgcn_mfma_f32_16x16x32_bf16(
                                a[m], bw[n], acc[m][n], 0, 0, 0);
    };

    bf16x8 a0[4], a1[4], a2[4], b0[4], b1[4], b2[4];
    LOADA(a0, 0); LOADB(b0, 0);
    LOADA(a1, 1); LOADB(b1, 1);
    LOADA(a2, 2); LOADB(b2, 2);
#pragma unroll
    for (int g = 0; g < 18; g += 3) {
        MFMAG(a0, b0);
        if (g + 3 < 18) { LOADA(a0, g + 3); LOADB(b0, g + 3); }
        MFMAG(a1, b1);
        if (g + 4 < 18) { LOADA(a1, g + 4); LOADB(b1, g + 4); }
        MFMAG(a2, b2);
        if (g + 5 < 18) { LOADA(a2, g + 5); LOADB(b2, g + 5); }
    }

    __syncthreads();                    // lds4 A-tile no longer needed
    float* htile = (float*)lds4;        // [64][CT_STRIDE] fp32

    // ---- LSTM pointwise epilogue (register -> LDS tiles) ----
    const int c = khalf * 16 + l15;                 // hid channel
    const int row = wrow * 32 + c;                  // transpose-tile row
#pragma unroll
    for (int m = 0; m < 4; ++m) {
#pragma unroll
        for (int rr = 0; rr < 4; ++rr) {
            const int p = m * 16 + lhi * 4 + rr;
            const float cp = t0 ? 0.f : ctile[row * CT_STRIDE + p];
            const float iv = acc[m][0][rr], fv = acc[m][1][rr];
            const float ov = acc[m][2][rr], gv = acc[m][3][rr];
            const float ig = __builtin_amdgcn_rcpf(1.f + __expf(-iv));
            const float fg = __builtin_amdgcn_rcpf(1.f + __expf(-fv));
            const float og = __builtin_amdgcn_rcpf(1.f + __expf(-ov));
            const float gg = 1.f - 2.f * __builtin_amdgcn_rcpf(1.f + __expf(2.f * gv));
            const float cn = fg * cp + ig * gg;
            const float hn = og * (1.f - 2.f * __builtin_amdgcn_rcpf(1.f + __expf(2.f * cn)));
            ctile[row * CT_STRIDE + p] = cn;
            htile[row * CT_STRIDE + p] = hn;
        }
    }
    __syncthreads();

    // ---- flush 1: htile -> hseq[t] / hT, ctile -> cbuf (coalesced) ----
#pragma unroll
    for (int j = 0; j < 4; ++j) {
        const int q = j * 4 + (tid & 3);
        const u32x4 hv = *(const u32x4*)(htile + fr * CT_STRIDE + q * 4);
        const uint4 cv = *(const uint4*)(ctile + fr * CT_STRIDE + q * 4);
        __builtin_nontemporal_store(hv, (u32x4*)(hout + gflat + q * 4));
        *(uint4*)(cbuf + gflat + q * 4) = cv;
        if (hT) __builtin_nontemporal_store(hv, (u32x4*)(hT + gflat + q * 4));
    }

    // ---- flush 2: htile -> hbf ping-pong, packed u64 coalesced stores ----
#pragma unroll
    for (int j = 0; j < 4; ++j) {
        const int idx = j * 256 + tid;       // 0..1023
        const int c4  = idx & 7;             // 4-channel group
        const int pxx = (idx >> 3) & 63;
        const int yy  = idx >> 9;
        u16 pk[4];
#pragma unroll
        for (int k = 0; k < 4; ++k)
            pk[k] = f2bf(htile[(yy * 32 + c4 * 4 + k) * CT_STRIDE + pxx]);
        const int pix = b * HWSZ + (y0 + yy) * WW + pxx;
        *(u64*)(hbfo + (size_t)pix * 32 + c4 * 4) = *(u64*)pk;
    }
}

__global__ __launch_bounds__(256, 2)
void fused_step(
    const u16* srcX0, const u16* srcH0, const uint4* wf0, const float* bias0,
    float* cbuf0, float* hout0, float* hT0, u16* hbfo0, int t00, int act0,
    const u16* srcX1, const u16* srcH1, const uint4* wf1, const float* bias1,
    float* cbuf1, float* hout1, float* hT1, u16* hbfo1, int t01, int act1)
{
    __shared__ uint4 lds4[2112];              // 33,792 B (A-tile, then htile)
    __shared__ float ctile[64 * CT_STRIDE];   // 17,408 B
    const int blk = blockIdx.x;
    if (blk < 256) {
        if (!act0) return;
        conv_step(srcX0, 16, srcH0, wf0, bias0, cbuf0, hout0, hT0, hbfo0, t00, blk, lds4, ctile);
    } else {
        if (!act1) return;
        conv_step(srcX1, 32, srcH1, wf1, bias1, cbuf1, hout1, hT1, hbfo1, t01, blk - 256, lds4, ctile);
    }
}

extern "C" void kernel_launch(void* const* d_in, const int* in_sizes, int n_in,
                              void* d_out, int out_size, void* d_ws, size_t ws_size,
                              hipStream_t stream) {
    const float* x  = (const float*)d_in[0];
    const float* W0 = (const float*)d_in[1];
    const float* b0 = (const float*)d_in[2];
    const float* W1 = (const float*)d_in[3];
    const float* b1 = (const float*)d_in[4];
    float* out = (float*)d_out;

    float* hseq0 = out;
    float* hseq1 = out + 16777216;
    float* h0T   = out + 33554432;
    float* c0T   = out + 34603008;   // running c, layer 0 (channel-major, in-place)
    float* h1T   = out + 35651584;
    float* c1T   = out + 36700160;   // running c, layer 1

    // ws layout (bytes): xbf 16,777,216 | wf0 147,456 | wf1 147,456 |
    //                    hbf0[2] 2x2,097,152 | hbf1[2] 2x2,097,152  = 25.5 MB
    char* ws = (char*)d_ws;
    u16*  xbf = (u16*)ws;
    u16*  wf0 = (u16*)(ws + 16777216);
    u16*  wf1 = (u16*)(ws + 16777216 + 147456);
    u16*  hbf0[2] = { (u16*)(ws + 17072128), (u16*)(ws + 17072128 + 2097152) };
    u16*  hbf1[2] = { (u16*)(ws + 21266432), (u16*)(ws + 21266432 + 2097152) };

    prep_x<<<2048, 256, 0, stream>>>(x, xbf);
    prep_w<<<36, 256, 0, stream>>>(W0, wf0, 48);
    prep_w<<<36, 256, 0, stream>>>(W1, wf1, 64);

    const size_t hstep = (size_t)BATCH * HID * HWSZ;   // 1,048,576 floats
    const size_t xstep = (size_t)BATCH * HWSZ * 16;    // bf16 elems per t

    for (int d = 0; d <= TT; ++d) {
        const int t0 = (d < TT) ? d : TT - 1;      // clamped (inactive half)
        const int t1 = (d >= 1) ? d - 1 : 0;
        const int act0 = (d < TT), act1 = (d >= 1);
        fused_step<<<512, 256, 0, stream>>>(
            // layer 0, time t0: x = xbf[t0], h_prev = hbf0[(t0-1)&1]
            xbf + (size_t)t0 * xstep, hbf0[(t0 - 1) & 1],
            (const uint4*)wf0, b0, c0T,
            hseq0 + (size_t)t0 * hstep, (t0 == TT - 1 && act0) ? h0T : nullptr,
            hbf0[t0 & 1], (t0 == 0) ? 1 : 0, act0,
            // layer 1, time t1: x = hbf0[t1&1], h_prev = hbf1[(t1-1)&1]
            hbf0[t1 & 1], hbf1[(t1 - 1) & 1],
            (const uint4*)wf1, b1, c1T,
            hseq1 + (size_t)t1 * hstep, (t1 == TT - 1 && act1) ? h1T : nullptr,
            hbf1[t1 & 1], (t1 == 0) ? 1 : 0, act1);
    }
}